// Round 17
// baseline (126.221 us; speedup 1.0000x reference)
//
#include <hip/hip_runtime.h>
#include <hip/hip_bf16.h>

#define B_   4
#define LQ_  900
#define D_   256
#define NH_  8
#define DH_  32
#define NL_  4
#define NP_  4
#define DFF_ 1024
#define LIN_ 21760
#define MQ_  (LQ_*B_)    // 3600
#define MV_  (LIN_*B_)   // 87040

typedef __attribute__((ext_vector_type(8))) short bh8;
typedef __attribute__((ext_vector_type(4))) float f32x4;

__device__ __forceinline__ short bf16b(float f) {
    __hip_bfloat16 h = __float2bfloat16(f);
    return *reinterpret_cast<short*>(&h);
}

__device__ __forceinline__ void gload_lds16(const void* g, void* l) {
    __builtin_amdgcn_global_load_lds(
        (const __attribute__((address_space(1))) unsigned int*)g,
        (__attribute__((address_space(3))) unsigned int*)l, 16, 0, 0);
}

__device__ __forceinline__ bh8 af_from_f32(const float* p) {
    float4 v0 = *reinterpret_cast<const float4*>(p);
    float4 v1 = *reinterpret_cast<const float4*>(p + 4);
    return (bh8){ bf16b(v0.x), bf16b(v0.y), bf16b(v0.z), bf16b(v0.w),
                  bf16b(v1.x), bf16b(v1.y), bf16b(v1.z), bf16b(v1.w) };
}

// ---- all weights -> MFMA B-frag images ----
__global__ __launch_bounds__(256)
void wprep_k(const float* __restrict__ Woff, const float* __restrict__ Wattn,
             const float* __restrict__ Wout, const float* __restrict__ W1,
             const float* __restrict__ W2, const float* __restrict__ Wval,
             unsigned char* __restrict__ qkvimg, unsigned char* __restrict__ outimg,
             unsigned char* __restrict__ w1img, unsigned char* __restrict__ w2img,
             unsigned char* __restrict__ valimg)
{
    const int cid = blockIdx.x*256 + threadIdx.x;   // 94208 total
    const float* W; unsigned char* img; int KQ, c;
    if      (cid < 8192)  { W=Woff;  img=qkvimg;           KQ=8;  c=cid;       }
    else if (cid < 12288) { W=Wattn; img=qkvimg + 131072;  KQ=8;  c=cid-8192;  }
    else if (cid < 20480) { W=Wout;  img=outimg;           KQ=8;  c=cid-12288; }
    else if (cid < 53248) { W=W1;    img=w1img;            KQ=8;  c=cid-20480; }
    else if (cid < 86016) { W=W2;    img=w2img;            KQ=32; c=cid-53248; }
    else                  { W=Wval;  img=valimg;           KQ=8;  c=cid-86016; }
    const int K   = KQ*32;
    const int n16 = c & 15, g = (c>>4)&3, t = c>>6;
    const int kq  = t & (KQ-1);
    const int ntile = t >> ((KQ==8) ? 3 : 5);
    const int n = ntile*16 + n16, k0 = kq*32 + g*8;
    float4 v0 = *reinterpret_cast<const float4*>(&W[(size_t)n*K + k0]);
    float4 v1 = *reinterpret_cast<const float4*>(&W[(size_t)n*K + k0 + 4]);
    union { short s[8]; uint4 u; } pk;
    pk.s[0]=bf16b(v0.x); pk.s[1]=bf16b(v0.y); pk.s[2]=bf16b(v0.z); pk.s[3]=bf16b(v0.w);
    pk.s[4]=bf16b(v1.x); pk.s[5]=bf16b(v1.y); pk.s[6]=bf16b(v1.z); pk.s[7]=bf16b(v1.w);
    *reinterpret_cast<uint4*>(img + (size_t)(ntile*KQ + kq)*1024 + (g*16+n16)*16) = pk.u;
}

// ---------------- value GEMM v8: high-TLP (8 blocks/CU), 4-slot A pipeline ----------------
// BM=32, BN=128 (bx&1 selects n-half), 256 thr (4 waves x 2 n-tiles).
// LDS 16 KB = 4 rotating A-chunk slots; A-prefetch 3 deep with A-only vmcnt counts
// (safe regardless of whether the compiler sinks the at-use W loads).
__global__ __launch_bounds__(256, 8)
void val_gemm_k(const float* __restrict__ A, const unsigned char* __restrict__ Wimg,
                const float* __restrict__ bias, unsigned short* __restrict__ C,
                const unsigned char* __restrict__ mask)
{
    __shared__ __align__(16) unsigned char Al[16384];   // 4 slots x 4 KB

    const int tid   = threadIdx.x;
    const int lane  = tid & 63;
    const int wc    = tid >> 6;          // 0..3
    const int mt    = blockIdx.x >> 1;
    const int nhalf = blockIdx.x & 1;
    const int m0    = mt * 32;
    const int r16   = lane & 15;
    const int g     = lane >> 4;

    const unsigned char* Abyte = (const unsigned char*)A;
    const unsigned char* wlane = Wimg + lane*16;

    const int a_row = (tid >> 3) & 31;
    const int a_x   = (tid & 7) * 16;
    const size_t a_src_row = (size_t)(m0 + a_row) * 1024 + (a_x ^ ((a_row & 7) << 4));
    const int a_dst = tid * 16;

#define ISSUE_A(KQ) gload_lds16(Abyte + a_src_row + (KQ)*128, (char*)Al + ((KQ)&3)*4096 + a_dst)

    // prologue: 3-deep A prefetch
    ISSUE_A(0);
    ISSUE_A(1);
    ISSUE_A(2);

    f32x4 acc[2][2];
    #pragma unroll
    for (int i = 0; i < 2; ++i)
        #pragma unroll
        for (int j = 0; j < 2; ++j) acc[i][j] = (f32x4){0.f,0.f,0.f,0.f};

    #pragma unroll
    for (int kq = 0; kq < 8; ++kq) {
        // A-only counted wait: A_kq retired, deeper A prefetch in flight.
        if (kq < 6)      asm volatile("s_waitcnt vmcnt(2)" ::: "memory");
        else if (kq == 6) asm volatile("s_waitcnt vmcnt(1)" ::: "memory");
        else              asm volatile("s_waitcnt vmcnt(0)" ::: "memory");
        __builtin_amdgcn_s_barrier();   // slot kq&3 resident for all waves

        bh8 af[2];
        #pragma unroll
        for (int mf = 0; mf < 2; ++mf) {
            const int row = mf*16 + r16;
            const int swz = (row & 7) << 4;
            const char* base = (const char*)Al + (kq & 3)*4096 + row*128;
            float4 v0 = *reinterpret_cast<const float4*>(base + ((g*32     ) ^ swz));
            float4 v1 = *reinterpret_cast<const float4*>(base + ((g*32 + 16) ^ swz));
            af[mf] = (bh8){ bf16b(v0.x), bf16b(v0.y), bf16b(v0.z), bf16b(v0.w),
                            bf16b(v1.x), bf16b(v1.y), bf16b(v1.z), bf16b(v1.w) };
        }

        // next A prefetch (slot (kq+3)&3 was last read in phase kq-1 -> safe after this barrier)
        if (kq < 5) ISSUE_A(kq + 3);

        // W fragments at use (TLP hides L2 latency)
        #pragma unroll
        for (int i = 0; i < 2; ++i) {
            const int nt = nhalf*8 + wc*2 + i;
            bh8 bf = *reinterpret_cast<const bh8*>(wlane + (size_t)(nt*8 + kq)*1024);
            #pragma unroll
            for (int mf = 0; mf < 2; ++mf)
                acc[mf][i] = __builtin_amdgcn_mfma_f32_16x16x32_bf16(af[mf], bf, acc[mf][i], 0, 0, 0);
        }
    }
#undef ISSUE_A

    float bv[2];
    #pragma unroll
    for (int i = 0; i < 2; ++i) bv[i] = bias[nhalf*128 + wc*32 + i*16 + r16];

    #pragma unroll
    for (int mf = 0; mf < 2; ++mf) {
        #pragma unroll
        for (int r = 0; r < 4; ++r) {
            const int gm = m0 + mf*16 + g*4 + r;
            const bool z = mask[(gm & 3)*LIN_ + (gm >> 2)] != 0;
            #pragma unroll
            for (int i = 0; i < 2; ++i) {
                float v = acc[mf][i][r] + bv[i];
                if (z) v = 0.f;
                C[(size_t)gm*256 + nhalf*128 + wc*32 + i*16 + r16] = (unsigned short)bf16b(v);
            }
        }
    }
}

// ---------------- fused off+attn projections ----------------
__global__ __launch_bounds__(512)
void qkv_k(const float* __restrict__ A, const unsigned char* __restrict__ Wimg,
           const float* __restrict__ b_off, const float* __restrict__ b_attn,
           float* __restrict__ Yoff, float* __restrict__ Yattn)
{
    const int tid = threadIdx.x, lane = tid & 63, w = tid >> 6;
    const int m16 = lane & 15, g = lane >> 4;
    const int m0 = blockIdx.x * 16;

    bh8 af[8];
    #pragma unroll
    for (int kq = 0; kq < 8; ++kq)
        af[kq] = af_from_f32(&A[(size_t)(m0 + m16)*256 + kq*32 + g*8]);

    f32x4 acc[3];
    #pragma unroll
    for (int i = 0; i < 3; ++i) acc[i] = (f32x4){0.f,0.f,0.f,0.f};

    #pragma unroll
    for (int i = 0; i < 3; ++i) {
        const int nt = w*3 + i;
        #pragma unroll
        for (int kq = 0; kq < 8; ++kq) {
            bh8 bf = *reinterpret_cast<const bh8*>(Wimg + (size_t)(nt*8 + kq)*1024 + lane*16);
            acc[i] = __builtin_amdgcn_mfma_f32_16x16x32_bf16(af[kq], bf, acc[i], 0, 0, 0);
        }
    }

    #pragma unroll
    for (int i = 0; i < 3; ++i) {
        const int nt = w*3 + i;
        const int j  = nt*16 + m16;
        #pragma unroll
        for (int r = 0; r < 4; ++r) {
            const int m = m0 + g*4 + r;
            if (nt < 16) Yoff[(size_t)m*256 + j] = acc[i][r] + b_off[j];
            else         Yattn[(size_t)m*128 + (j-256)] = acc[i][r] + b_attn[j-256];
        }
    }
}

// ---------------- out-proj + add-tgt + LN1: 1024 thr, 1 n-tile per wave ----------------
__global__ __launch_bounds__(1024, 4)
void outln_k(const float* __restrict__ A, const unsigned char* __restrict__ Wimg,
             const float* __restrict__ bias, const float* __restrict__ res,
             const float* __restrict__ lg, const float* __restrict__ lb,
             float* __restrict__ T)
{
    __shared__ float sln[16][256];

    const int tid = threadIdx.x, lane = tid & 63, w = tid >> 6;
    const int m16 = lane & 15, g = lane >> 4;
    const int m0 = blockIdx.x * 16;

    bh8 af[8];
    #pragma unroll
    for (int kq = 0; kq < 8; ++kq)
        af[kq] = af_from_f32(&A[(size_t)(m0 + m16)*256 + kq*32 + g*8]);

    f32x4 acc = (f32x4){0.f,0.f,0.f,0.f};
    #pragma unroll
    for (int kq = 0; kq < 8; ++kq) {
        bh8 bf = *reinterpret_cast<const bh8*>(Wimg + (size_t)(w*8 + kq)*1024 + lane*16);
        acc = __builtin_amdgcn_mfma_f32_16x16x32_bf16(af[kq], bf, acc, 0, 0, 0);
    }

    const int j = w*16 + m16;
    #pragma unroll
    for (int r = 0; r < 4; ++r) {
        const int ml = g*4 + r;
        sln[ml][j] = acc[r] + bias[j] + res[(size_t)(m0 + ml)*256 + j];
    }
    __syncthreads();

    const int row = tid >> 6, l2 = tid & 63;
    float v[4], s1 = 0.f, s2 = 0.f;
    #pragma unroll
    for (int c = 0; c < 4; ++c) {
        v[c] = sln[row][l2 + c*64];
        s1 += v[c]; s2 += v[c]*v[c];
    }
    #pragma unroll
    for (int o = 32; o >= 1; o >>= 1) {
        s1 += __shfl_xor(s1, o, 64);
        s2 += __shfl_xor(s2, o, 64);
    }
    const float mu  = s1 * (1.f/256.f);
    const float var = s2 * (1.f/256.f) - mu*mu;
    const float is  = rsqrtf(var + 1e-5f);
    #pragma unroll
    for (int c = 0; c < 4; ++c) {
        const int jj = l2 + c*64;
        T[(size_t)(m0 + row)*256 + jj] = (v[c] - mu) * is * lg[jj] + lb[jj];
    }
}

// ---------------- FFN + LN3: 1024 thr, 16 waves, 4 f-chunk rounds ----------------
__global__ __launch_bounds__(1024, 4)
void ffnln_k(const float* __restrict__ T, const unsigned char* __restrict__ W1img,
             const float* __restrict__ b1, const unsigned char* __restrict__ W2img,
             const float* __restrict__ b2, const float* __restrict__ lg,
             const float* __restrict__ lb, float* __restrict__ Yout)
{
    __shared__ __align__(16) short hl[2][16*272];
    __shared__ float sln[16][256];

    const int tid = threadIdx.x, lane = tid & 63, w = tid >> 6;
    const int m16 = lane & 15, g = lane >> 4;
    const int m0 = blockIdx.x * 16;

    bh8 af1[8];
    #pragma unroll
    for (int kq = 0; kq < 8; ++kq)
        af1[kq] = af_from_f32(&T[(size_t)(m0 + m16)*256 + kq*32 + g*8]);

    f32x4 yacc = (f32x4){0.f,0.f,0.f,0.f};

    int buf = 0;
    #pragma unroll
    for (int fc = 0; fc < 4; ++fc) {
        const int ftile_g = fc*16 + w;
        f32x4 hacc = (f32x4){0.f,0.f,0.f,0.f};
        #pragma unroll
        for (int kq = 0; kq < 8; ++kq) {
            bh8 bf = *reinterpret_cast<const bh8*>(W1img + (size_t)(ftile_g*8 + kq)*1024 + lane*16);
            hacc = __builtin_amdgcn_mfma_f32_16x16x32_bf16(af1[kq], bf, hacc, 0, 0, 0);
        }
        const float bb = b1[ftile_g*16 + m16];
        #pragma unroll
        for (int r = 0; r < 4; ++r) {
            const float v = fmaxf(hacc[r] + bb, 0.f);
            hl[buf][(g*4 + r)*272 + w*16 + m16] = bf16b(v);
        }
        __syncthreads();
        bh8 a2[8];
        #pragma unroll
        for (int kqf = 0; kqf < 8; ++kqf)
            a2[kqf] = *reinterpret_cast<const bh8*>((const char*)&hl[buf][0]
                + m16*544 + (kqf*32 + g*8)*2);
        #pragma unroll
        for (int kqf = 0; kqf < 8; ++kqf) {
            const int kq2 = fc*8 + kqf;
            bh8 bf = *reinterpret_cast<const bh8*>(W2img + (size_t)(w*32 + kq2)*1024 + lane*16);
            yacc = __builtin_amdgcn_mfma_f32_16x16x32_bf16(a2[kqf], bf, yacc, 0, 0, 0);
        }
        buf ^= 1;
    }

    const int j = w*16 + m16;
    #pragma unroll
    for (int r = 0; r < 4; ++r) {
        const int ml = g*4 + r;
        sln[ml][j] = yacc[r] + b2[j] + T[(size_t)(m0 + ml)*256 + j];
    }
    __syncthreads();

    const int row = tid >> 6, l2 = tid & 63;
    float v[4], s1 = 0.f, s2 = 0.f;
    #pragma unroll
    for (int c = 0; c < 4; ++c) {
        v[c] = sln[row][l2 + c*64];
        s1 += v[c]; s2 += v[c]*v[c];
    }
    #pragma unroll
    for (int o = 32; o >= 1; o >>= 1) {
        s1 += __shfl_xor(s1, o, 64);
        s2 += __shfl_xor(s2, o, 64);
    }
    const float mu  = s1 * (1.f/256.f);
    const float var = s2 * (1.f/256.f) - mu*mu;
    const float is  = rsqrtf(var + 1e-5f);
    #pragma unroll
    for (int c = 0; c < 4; ++c) {
        const int jj = l2 + c*64;
        Yout[(size_t)(m0 + row)*256 + jj] = (v[c] - mu) * is * lg[jj] + lb[jj];
    }
}

// ---------------- deformable sampling ----------------
__global__ __launch_bounds__(256)
void msda_k(const float* __restrict__ off,
            const float* __restrict__ attnlog,
            const float* __restrict__ refp,
            const __hip_bfloat16* __restrict__ value,
            float* __restrict__ out)
{
    const int m = blockIdx.x;
    const int b = m & 3;
    const int d = threadIdx.x;
    const int h = d >> 5;

    __shared__ float s_off[256];
    __shared__ float s_al[128];
    __shared__ float s_ref[NL_*2];
    s_off[d] = off[(size_t)m*256 + d];
    if (d < 128) s_al[d] = attnlog[(size_t)m*128 + d];
    if (d < NL_*2) s_ref[d] = refp[(size_t)m*(NL_*2) + d];
    __syncthreads();

    float mx = -1e30f;
    #pragma unroll
    for (int t = 0; t < 16; ++t) mx = fmaxf(mx, s_al[h*16 + t]);
    float e[16], ssum = 0.f;
    #pragma unroll
    for (int t = 0; t < 16; ++t) { e[t] = __expf(s_al[h*16 + t] - mx); ssum += e[t]; }
    const float inv = 1.f / ssum;

    const int HS[4] = {128, 64, 32, 16};
    const int ST[4] = {0, 16384, 20480, 21504};

    float acc = 0.f;
    #pragma unroll
    for (int l = 0; l < NL_; ++l) {
        const int H = HS[l], W = HS[l], st = ST[l];
        const float rx = s_ref[l*2+0], ry = s_ref[l*2+1];
        #pragma unroll
        for (int p = 0; p < NP_; ++p) {
            const int base = ((h*NL_ + l)*NP_ + p);
            const float a  = e[l*4 + p] * inv;
            const float ox = s_off[base*2+0], oy = s_off[base*2+1];
            const float x = rx*(float)W + ox - 0.5f;
            const float y = ry*(float)H + oy - 0.5f;
            const float x0f = floorf(x), y0f = floorf(y);
            const int x0 = (int)x0f, y0 = (int)y0f;
            const float wx1 = x - x0f, wy1 = y - y0f;
            const float wx0 = 1.f - wx1, wy0 = 1.f - wy1;
            #pragma unroll
            for (int t = 0; t < 4; ++t) {
                const int xi = x0 + (t & 1);
                const int yi = y0 + (t >> 1);
                const float wgt = (t==0 ? wx0*wy0 : t==1 ? wx1*wy0 : t==2 ? wx0*wy1 : wx1*wy1);
                if (xi >= 0 && xi < W && yi >= 0 && yi < H) {
                    const size_t idx = (size_t)(st + yi*W + xi);
                    const float v = __bfloat162float(value[(idx*B_ + b)*D_ + d]);
                    acc = fmaf(a*wgt, v, acc);
                }
            }
        }
    }
    out[(size_t)m*256 + d] = acc;
}

extern "C" void kernel_launch(void* const* d_in, const int* in_sizes, int n_in,
                              void* d_out, int out_size, void* d_ws, size_t ws_size,
                              hipStream_t stream)
{
    const float* tgt    = (const float*)d_in[0];
    const float* refp   = (const float*)d_in[1];
    const float* mem    = (const float*)d_in[2];
    const float* W_off  = (const float*)d_in[3];
    const float* b_off  = (const float*)d_in[4];
    const float* W_attn = (const float*)d_in[5];
    const float* b_attn = (const float*)d_in[6];
    const float* W_val  = (const float*)d_in[7];
    const float* b_val  = (const float*)d_in[8];
    const float* W_out  = (const float*)d_in[9];
    const float* b_out  = (const float*)d_in[10];
    const float* ln1g   = (const float*)d_in[11];
    const float* ln1b   = (const float*)d_in[12];
    const float* W1     = (const float*)d_in[13];
    const float* b1     = (const float*)d_in[14];
    const float* W2     = (const float*)d_in[15];
    const float* b2     = (const float*)d_in[16];
    const float* ln3g   = (const float*)d_in[17];
    const float* ln3b   = (const float*)d_in[18];
    const unsigned char* mask = (const unsigned char*)d_in[21];
    float* out = (float*)d_out;

    char* p = (char*)d_ws;
    __hip_bfloat16* value = (__hip_bfloat16*)p; p += (size_t)MV_*D_*2;   // 44.6 MB
    float* offb = (float*)p; p += (size_t)MQ_*256*4;
    float* attl = (float*)p; p += (size_t)MQ_*128*4;
    float* msda = (float*)p; p += (size_t)MQ_*256*4;
    float* tb   = (float*)p; p += (size_t)MQ_*256*4;
    unsigned char* qkvimg = (unsigned char*)p; p += 196608;
    unsigned char* outimg = (unsigned char*)p; p += 131072;
    unsigned char* w1img  = (unsigned char*)p; p += 524288;
    unsigned char* w2img  = (unsigned char*)p; p += 524288;
    unsigned char* valimg = (unsigned char*)p; p += 131072;
    (void)ws_size; (void)in_sizes; (void)n_in; (void)out_size;

    // 0) weight B-frag images
    wprep_k<<<dim3(368), dim3(256), 0, stream>>>(W_off, W_attn, W_out, W1, W2, W_val,
                                                 qkvimg, outimg, w1img, w2img, valimg);
    // 1) value projection: high-TLP v8 (8 blocks/CU)
    val_gemm_k<<<dim3((MV_/32)*2), dim3(256), 0, stream>>>(mem, valimg, b_val,
                                                           (unsigned short*)value, mask);
    // 2+3) off + attn logits, fused
    qkv_k<<<dim3(MQ_/16), dim3(512), 0, stream>>>(tgt, qkvimg, b_off, b_attn, offb, attl);
    // 4) deformable sampling
    msda_k<<<dim3(MQ_), dim3(256), 0, stream>>>(offb, attl, refp, value, msda);
    // 5+6) ca = msda @ W_out^T + b_out ; tb = LN(tgt + ca)
    outln_k<<<dim3(MQ_/16), dim3(1024), 0, stream>>>(msda, outimg, b_out, tgt, ln1g, ln1b, tb);
    // 7+8+9) FFN + LN3 fully fused -> out
    ffnln_k<<<dim3(MQ_/16), dim3(1024), 0, stream>>>(tb, w1img, b1, w2img, b2, ln3g, ln3b, out);
}

// Round 18
// 115.686 us; speedup vs baseline: 1.0911x; 1.0911x over previous
//
#include <hip/hip_runtime.h>
#include <hip/hip_bf16.h>

#define B_   4
#define LQ_  900
#define D_   256
#define NH_  8
#define DH_  32
#define NL_  4
#define NP_  4
#define DFF_ 1024
#define LIN_ 21760
#define MQ_  (LQ_*B_)    // 3600
#define MV_  (LIN_*B_)   // 87040
#define VALBLKS (MV_/32) // 2720

typedef __attribute__((ext_vector_type(8))) short bh8;
typedef __attribute__((ext_vector_type(4))) float f32x4;

__device__ __forceinline__ short bf16b(float f) {
    __hip_bfloat16 h = __float2bfloat16(f);
    return *reinterpret_cast<short*>(&h);
}

__device__ __forceinline__ void gload_lds16(const void* g, void* l) {
    __builtin_amdgcn_global_load_lds(
        (const __attribute__((address_space(1))) unsigned int*)g,
        (__attribute__((address_space(3))) unsigned int*)l, 16, 0, 0);
}

__device__ __forceinline__ bh8 af_from_f32(const float* p) {
    float4 v0 = *reinterpret_cast<const float4*>(p);
    float4 v1 = *reinterpret_cast<const float4*>(p + 4);
    return (bh8){ bf16b(v0.x), bf16b(v0.y), bf16b(v0.z), bf16b(v0.w),
                  bf16b(v1.x), bf16b(v1.y), bf16b(v1.z), bf16b(v1.w) };
}

// ---- all weights -> MFMA B-frag images ----
__global__ __launch_bounds__(256)
void wprep_k(const float* __restrict__ Woff, const float* __restrict__ Wattn,
             const float* __restrict__ Wout, const float* __restrict__ W1,
             const float* __restrict__ W2, const float* __restrict__ Wval,
             unsigned char* __restrict__ qkvimg, unsigned char* __restrict__ outimg,
             unsigned char* __restrict__ w1img, unsigned char* __restrict__ w2img,
             unsigned char* __restrict__ valimg)
{
    const int cid = blockIdx.x*256 + threadIdx.x;   // 94208 total
    const float* W; unsigned char* img; int KQ, c;
    if      (cid < 8192)  { W=Woff;  img=qkvimg;           KQ=8;  c=cid;       }
    else if (cid < 12288) { W=Wattn; img=qkvimg + 131072;  KQ=8;  c=cid-8192;  }
    else if (cid < 20480) { W=Wout;  img=outimg;           KQ=8;  c=cid-12288; }
    else if (cid < 53248) { W=W1;    img=w1img;            KQ=8;  c=cid-20480; }
    else if (cid < 86016) { W=W2;    img=w2img;            KQ=32; c=cid-53248; }
    else                  { W=Wval;  img=valimg;           KQ=8;  c=cid-86016; }
    const int K   = KQ*32;
    const int n16 = c & 15, g = (c>>4)&3, t = c>>6;
    const int kq  = t & (KQ-1);
    const int ntile = t >> ((KQ==8) ? 3 : 5);
    const int n = ntile*16 + n16, k0 = kq*32 + g*8;
    float4 v0 = *reinterpret_cast<const float4*>(&W[(size_t)n*K + k0]);
    float4 v1 = *reinterpret_cast<const float4*>(&W[(size_t)n*K + k0 + 4]);
    union { short s[8]; uint4 u; } pk;
    pk.s[0]=bf16b(v0.x); pk.s[1]=bf16b(v0.y); pk.s[2]=bf16b(v0.z); pk.s[3]=bf16b(v0.w);
    pk.s[4]=bf16b(v1.x); pk.s[5]=bf16b(v1.y); pk.s[6]=bf16b(v1.z); pk.s[7]=bf16b(v1.w);
    *reinterpret_cast<uint4*>(img + (size_t)(ntile*KQ + kq)*1024 + (g*16+n16)*16) = pk.u;
}

// ---------------- value GEMM (R14 body) + qkv tail blocks ----------------
__global__ __launch_bounds__(256, 4)
void valqkv_k(const float* __restrict__ A, const unsigned char* __restrict__ Wimg,
              const float* __restrict__ bias, unsigned short* __restrict__ C,
              const unsigned char* __restrict__ mask,
              const float* __restrict__ tgt, const unsigned char* __restrict__ Qimg,
              const float* __restrict__ b_off, const float* __restrict__ b_attn,
              float* __restrict__ Yoff, float* __restrict__ Yattn)
{
    __shared__ __align__(16) unsigned char Al[32768];

    const int tid  = threadIdx.x;
    const int lane = tid & 63;

    if (blockIdx.x < VALBLKS) {
        // ============ value projection: R14 8-phase counted-vmcnt body ============
        const int wc   = tid >> 6;
        const int m0   = blockIdx.x * 32;
        const int r16  = lane & 15;
        const int g    = lane >> 4;

        const unsigned char* Abyte = (const unsigned char*)A;
        const unsigned char* wlane = Wimg + lane*16;

        const int a_row = (tid >> 3) & 31;
        const int a_x   = (tid & 7) * 16;
        const size_t a_src_row = (size_t)(m0 + a_row) * 1024 + (a_x ^ ((a_row & 7) << 4));
        const int a_dst = tid * 16;

#define ISSUE_A(KQ) gload_lds16(Abyte + a_src_row + (KQ)*128, (char*)Al + (KQ)*4096 + a_dst)
#define ISSUE_W(KQ, SLOT)                                                              \
    do { _Pragma("unroll")                                                             \
        for (int i_ = 0; i_ < 4; ++i_)                                                 \
            bfr[SLOT][i_] = *reinterpret_cast<const bh8*>(                             \
                wlane + (size_t)((wc*4 + i_)*8 + (KQ))*1024);                          \
    } while (0)

        bh8 bfr[3][4];

        ISSUE_A(0);
        ISSUE_W(0, 0);
        ISSUE_W(1, 1);
        ISSUE_A(1);
        ISSUE_A(2);

        f32x4 acc[2][4];
        #pragma unroll
        for (int i = 0; i < 2; ++i)
            #pragma unroll
            for (int j = 0; j < 4; ++j) acc[i][j] = (f32x4){0.f,0.f,0.f,0.f};

        #pragma unroll
        for (int kq = 0; kq < 8; ++kq) {
            if (kq < 6)      asm volatile("s_waitcnt vmcnt(6)" ::: "memory");
            else if (kq == 6) asm volatile("s_waitcnt vmcnt(5)" ::: "memory");
            else              asm volatile("s_waitcnt vmcnt(0)" ::: "memory");
            __builtin_amdgcn_s_barrier();

            bh8 af[2];
            #pragma unroll
            for (int mf = 0; mf < 2; ++mf) {
                const int row = mf*16 + r16;
                const int swz = (row & 7) << 4;
                const char* base = (const char*)Al + kq*4096 + row*128;
                float4 v0 = *reinterpret_cast<const float4*>(base + ((g*32     ) ^ swz));
                float4 v1 = *reinterpret_cast<const float4*>(base + ((g*32 + 16) ^ swz));
                af[mf] = (bh8){ bf16b(v0.x), bf16b(v0.y), bf16b(v0.z), bf16b(v0.w),
                                bf16b(v1.x), bf16b(v1.y), bf16b(v1.z), bf16b(v1.w) };
            }

            if (kq == 0) { ISSUE_W(2, 2); ISSUE_A(3); }
            if (kq == 1) { ISSUE_W(3, 0); ISSUE_A(4); }
            if (kq == 2) { ISSUE_W(4, 1); ISSUE_A(5); }
            if (kq == 3) { ISSUE_W(5, 2); ISSUE_A(6); }
            if (kq == 4) { ISSUE_W(6, 0); ISSUE_A(7); }
            if (kq == 5) { ISSUE_W(7, 1); }

            #pragma unroll
            for (int mf = 0; mf < 2; ++mf)
                #pragma unroll
                for (int i = 0; i < 4; ++i)
                    acc[mf][i] = __builtin_amdgcn_mfma_f32_16x16x32_bf16(af[mf], bfr[kq % 3][i], acc[mf][i], 0, 0, 0);
        }
#undef ISSUE_A
#undef ISSUE_W

        float bv[4];
        #pragma unroll
        for (int i = 0; i < 4; ++i) bv[i] = bias[wc*64 + i*16 + r16];

        #pragma unroll
        for (int mf = 0; mf < 2; ++mf) {
            #pragma unroll
            for (int r = 0; r < 4; ++r) {
                const int gm = m0 + mf*16 + g*4 + r;
                const bool z = mask[(gm & 3)*LIN_ + (gm >> 2)] != 0;
                #pragma unroll
                for (int i = 0; i < 4; ++i) {
                    float v = acc[mf][i][r] + bv[i];
                    if (z) v = 0.f;
                    C[(size_t)gm*256 + wc*64 + i*16 + r16] = (unsigned short)bf16b(v);
                }
            }
        }
    } else {
        // ============ qkv: off+attn projections, 4 waves x 6 n-tiles ============
        const int w   = tid >> 6;            // 0..3
        const int m16 = lane & 15, g = lane >> 4;
        const int m0  = (blockIdx.x - VALBLKS) * 16;

        bh8 af[8];
        #pragma unroll
        for (int kq = 0; kq < 8; ++kq)
            af[kq] = af_from_f32(&tgt[(size_t)(m0 + m16)*256 + kq*32 + g*8]);

        f32x4 acc[6];
        #pragma unroll
        for (int i = 0; i < 6; ++i) acc[i] = (f32x4){0.f,0.f,0.f,0.f};

        #pragma unroll
        for (int i = 0; i < 6; ++i) {
            const int nt = w*6 + i;          // 0..23
            #pragma unroll
            for (int kq = 0; kq < 8; ++kq) {
                bh8 bf = *reinterpret_cast<const bh8*>(Qimg + (size_t)(nt*8 + kq)*1024 + lane*16);
                acc[i] = __builtin_amdgcn_mfma_f32_16x16x32_bf16(af[kq], bf, acc[i], 0, 0, 0);
            }
        }

        #pragma unroll
        for (int i = 0; i < 6; ++i) {
            const int nt = w*6 + i;
            const int j  = nt*16 + m16;
            #pragma unroll
            for (int r = 0; r < 4; ++r) {
                const int m = m0 + g*4 + r;
                if (nt < 16) Yoff[(size_t)m*256 + j] = acc[i][r] + b_off[j];
                else         Yattn[(size_t)m*128 + (j-256)] = acc[i][r] + b_attn[j-256];
            }
        }
    }
}

// ---------------- fused out-proj + LN1 + FFN + LN3 (tb never leaves LDS) ----------------
// 1024 thr, grid 225 (<=1 block/CU). Phase1: out-proj+residual+LN1 -> sln (fp32 LDS).
// Phase2: FFN on sln; epilogue adds sln residual, LN3, writes out.
__global__ __launch_bounds__(1024, 2)
void outffn_k(const float* __restrict__ Amsda, const unsigned char* __restrict__ Oimg,
              const float* __restrict__ b_out, const float* __restrict__ res,
              const float* __restrict__ l1g, const float* __restrict__ l1b,
              const unsigned char* __restrict__ W1img, const float* __restrict__ b1,
              const unsigned char* __restrict__ W2img, const float* __restrict__ b2,
              const float* __restrict__ l3g, const float* __restrict__ l3b,
              float* __restrict__ Yout)
{
    __shared__ float sln[16][256];                  // t buffer (16 KB)
    __shared__ __align__(16) short hl[2][16*272];   // h chunks (17 KB)

    const int tid = threadIdx.x, lane = tid & 63, w = tid >> 6;   // w = 0..15
    const int m16 = lane & 15, g = lane >> 4;
    const int m0 = blockIdx.x * 16;

    // ---- phase 1: out-proj (wave w = n-tile w) ----
    {
        bh8 af[8];
        #pragma unroll
        for (int kq = 0; kq < 8; ++kq)
            af[kq] = af_from_f32(&Amsda[(size_t)(m0 + m16)*256 + kq*32 + g*8]);

        f32x4 acc = (f32x4){0.f,0.f,0.f,0.f};
        #pragma unroll
        for (int kq = 0; kq < 8; ++kq) {
            bh8 bf = *reinterpret_cast<const bh8*>(Oimg + (size_t)(w*8 + kq)*1024 + lane*16);
            acc = __builtin_amdgcn_mfma_f32_16x16x32_bf16(af[kq], bf, acc, 0, 0, 0);
        }

        const int j = w*16 + m16;
        #pragma unroll
        for (int r = 0; r < 4; ++r) {
            const int ml = g*4 + r;
            sln[ml][j] = acc[r] + b_out[j] + res[(size_t)(m0 + ml)*256 + j];
        }
    }
    __syncthreads();

    // ---- LN1 in place: row w, 64 lanes x 4 cols ----
    {
        const int row = w, l2 = lane;
        float v[4], s1 = 0.f, s2 = 0.f;
        #pragma unroll
        for (int c = 0; c < 4; ++c) {
            v[c] = sln[row][l2 + c*64];
            s1 += v[c]; s2 += v[c]*v[c];
        }
        #pragma unroll
        for (int o = 32; o >= 1; o >>= 1) {
            s1 += __shfl_xor(s1, o, 64);
            s2 += __shfl_xor(s2, o, 64);
        }
        const float mu  = s1 * (1.f/256.f);
        const float var = s2 * (1.f/256.f) - mu*mu;
        const float is  = rsqrtf(var + 1e-5f);
        #pragma unroll
        for (int c = 0; c < 4; ++c) {
            const int jj = l2 + c*64;
            sln[row][jj] = (v[c] - mu) * is * l1g[jj] + l1b[jj];
        }
    }
    __syncthreads();

    // ---- phase 2: FFN on LDS-resident t ----
    bh8 af1[8];
    #pragma unroll
    for (int kq = 0; kq < 8; ++kq)
        af1[kq] = af_from_f32(&sln[m16][kq*32 + g*8]);

    f32x4 yacc = (f32x4){0.f,0.f,0.f,0.f};

    int buf = 0;
    #pragma unroll
    for (int fc = 0; fc < 4; ++fc) {
        const int ftile_g = fc*16 + w;
        f32x4 hacc = (f32x4){0.f,0.f,0.f,0.f};
        #pragma unroll
        for (int kq = 0; kq < 8; ++kq) {
            bh8 bf = *reinterpret_cast<const bh8*>(W1img + (size_t)(ftile_g*8 + kq)*1024 + lane*16);
            hacc = __builtin_amdgcn_mfma_f32_16x16x32_bf16(af1[kq], bf, hacc, 0, 0, 0);
        }
        const float bb = b1[ftile_g*16 + m16];
        #pragma unroll
        for (int r = 0; r < 4; ++r) {
            const float v = fmaxf(hacc[r] + bb, 0.f);
            hl[buf][(g*4 + r)*272 + w*16 + m16] = bf16b(v);
        }
        __syncthreads();
        bh8 a2[8];
        #pragma unroll
        for (int kqf = 0; kqf < 8; ++kqf)
            a2[kqf] = *reinterpret_cast<const bh8*>((const char*)&hl[buf][0]
                + m16*544 + (kqf*32 + g*8)*2);
        #pragma unroll
        for (int kqf = 0; kqf < 8; ++kqf) {
            const int kq2 = fc*8 + kqf;
            bh8 bf = *reinterpret_cast<const bh8*>(W2img + (size_t)(w*32 + kq2)*1024 + lane*16);
            yacc = __builtin_amdgcn_mfma_f32_16x16x32_bf16(a2[kqf], bf, yacc, 0, 0, 0);
        }
        buf ^= 1;
    }

    // ---- epilogue: y + b2 + t (in-place, one-to-one), LN3, write out ----
    {
        const int j = w*16 + m16;
        #pragma unroll
        for (int r = 0; r < 4; ++r) {
            const int ml = g*4 + r;
            sln[ml][j] = yacc[r] + b2[j] + sln[ml][j];
        }
    }
    __syncthreads();

    {
        const int row = w, l2 = lane;
        float v[4], s1 = 0.f, s2 = 0.f;
        #pragma unroll
        for (int c = 0; c < 4; ++c) {
            v[c] = sln[row][l2 + c*64];
            s1 += v[c]; s2 += v[c]*v[c];
        }
        #pragma unroll
        for (int o = 32; o >= 1; o >>= 1) {
            s1 += __shfl_xor(s1, o, 64);
            s2 += __shfl_xor(s2, o, 64);
        }
        const float mu  = s1 * (1.f/256.f);
        const float var = s2 * (1.f/256.f) - mu*mu;
        const float is  = rsqrtf(var + 1e-5f);
        #pragma unroll
        for (int c = 0; c < 4; ++c) {
            const int jj = l2 + c*64;
            Yout[(size_t)(m0 + row)*256 + jj] = (v[c] - mu) * is * l3g[jj] + l3b[jj];
        }
    }
}

// ---------------- deformable sampling ----------------
__global__ __launch_bounds__(256)
void msda_k(const float* __restrict__ off,
            const float* __restrict__ attnlog,
            const float* __restrict__ refp,
            const __hip_bfloat16* __restrict__ value,
            float* __restrict__ out)
{
    const int m = blockIdx.x;
    const int b = m & 3;
    const int d = threadIdx.x;
    const int h = d >> 5;

    __shared__ float s_off[256];
    __shared__ float s_al[128];
    __shared__ float s_ref[NL_*2];
    s_off[d] = off[(size_t)m*256 + d];
    if (d < 128) s_al[d] = attnlog[(size_t)m*128 + d];
    if (d < NL_*2) s_ref[d] = refp[(size_t)m*(NL_*2) + d];
    __syncthreads();

    float mx = -1e30f;
    #pragma unroll
    for (int t = 0; t < 16; ++t) mx = fmaxf(mx, s_al[h*16 + t]);
    float e[16], ssum = 0.f;
    #pragma unroll
    for (int t = 0; t < 16; ++t) { e[t] = __expf(s_al[h*16 + t] - mx); ssum += e[t]; }
    const float inv = 1.f / ssum;

    const int HS[4] = {128, 64, 32, 16};
    const int ST[4] = {0, 16384, 20480, 21504};

    float acc = 0.f;
    #pragma unroll
    for (int l = 0; l < NL_; ++l) {
        const int H = HS[l], W = HS[l], st = ST[l];
        const float rx = s_ref[l*2+0], ry = s_ref[l*2+1];
        #pragma unroll
        for (int p = 0; p < NP_; ++p) {
            const int base = ((h*NL_ + l)*NP_ + p);
            const float a  = e[l*4 + p] * inv;
            const float ox = s_off[base*2+0], oy = s_off[base*2+1];
            const float x = rx*(float)W + ox - 0.5f;
            const float y = ry*(float)H + oy - 0.5f;
            const float x0f = floorf(x), y0f = floorf(y);
            const int x0 = (int)x0f, y0 = (int)y0f;
            const float wx1 = x - x0f, wy1 = y - y0f;
            const float wx0 = 1.f - wx1, wy0 = 1.f - wy1;
            #pragma unroll
            for (int t = 0; t < 4; ++t) {
                const int xi = x0 + (t & 1);
                const int yi = y0 + (t >> 1);
                const float wgt = (t==0 ? wx0*wy0 : t==1 ? wx1*wy0 : t==2 ? wx0*wy1 : wx1*wy1);
                if (xi >= 0 && xi < W && yi >= 0 && yi < H) {
                    const size_t idx = (size_t)(st + yi*W + xi);
                    const float v = __bfloat162float(value[(idx*B_ + b)*D_ + d]);
                    acc = fmaf(a*wgt, v, acc);
                }
            }
        }
    }
    out[(size_t)m*256 + d] = acc;
}

extern "C" void kernel_launch(void* const* d_in, const int* in_sizes, int n_in,
                              void* d_out, int out_size, void* d_ws, size_t ws_size,
                              hipStream_t stream)
{
    const float* tgt    = (const float*)d_in[0];
    const float* refp   = (const float*)d_in[1];
    const float* mem    = (const float*)d_in[2];
    const float* W_off  = (const float*)d_in[3];
    const float* b_off  = (const float*)d_in[4];
    const float* W_attn = (const float*)d_in[5];
    const float* b_attn = (const float*)d_in[6];
    const float* W_val  = (const float*)d_in[7];
    const float* b_val  = (const float*)d_in[8];
    const float* W_out  = (const float*)d_in[9];
    const float* b_out  = (const float*)d_in[10];
    const float* ln1g   = (const float*)d_in[11];
    const float* ln1b   = (const float*)d_in[12];
    const float* W1     = (const float*)d_in[13];
    const float* b1     = (const float*)d_in[14];
    const float* W2     = (const float*)d_in[15];
    const float* b2     = (const float*)d_in[16];
    const float* ln3g   = (const float*)d_in[17];
    const float* ln3b   = (const float*)d_in[18];
    const unsigned char* mask = (const unsigned char*)d_in[21];
    float* out = (float*)d_out;

    char* p = (char*)d_ws;
    __hip_bfloat16* value = (__hip_bfloat16*)p; p += (size_t)MV_*D_*2;   // 44.6 MB
    float* offb = (float*)p; p += (size_t)MQ_*256*4;
    float* attl = (float*)p; p += (size_t)MQ_*128*4;
    float* msda = (float*)p; p += (size_t)MQ_*256*4;
    unsigned char* qkvimg = (unsigned char*)p; p += 196608;
    unsigned char* outimg = (unsigned char*)p; p += 131072;
    unsigned char* w1img  = (unsigned char*)p; p += 524288;
    unsigned char* w2img  = (unsigned char*)p; p += 524288;
    unsigned char* valimg = (unsigned char*)p; p += 131072;
    (void)ws_size; (void)in_sizes; (void)n_in; (void)out_size;

    // 0) weight B-frag images
    wprep_k<<<dim3(368), dim3(256), 0, stream>>>(W_off, W_attn, W_out, W1, W2, W_val,
                                                 qkvimg, outimg, w1img, w2img, valimg);
    // 1) value projection + qkv projections (one dispatch)
    valqkv_k<<<dim3(VALBLKS + MQ_/16), dim3(256), 0, stream>>>(
        mem, valimg, b_val, (unsigned short*)value, mask,
        tgt, qkvimg, b_off, b_attn, offb, attl);
    // 2) deformable sampling
    msda_k<<<dim3(MQ_), dim3(256), 0, stream>>>(offb, attl, refp, value, msda);
    // 3) out-proj + LN1 + FFN + LN3 (one dispatch) -> out
    outffn_k<<<dim3(MQ_/16), dim3(1024), 0, stream>>>(
        msda, outimg, b_out, tgt, ln1g, ln1b,
        w1img, b1, w2img, b2, ln3g, ln3b, out);
}

// Round 19
// 112.073 us; speedup vs baseline: 1.1262x; 1.0322x over previous
//
#include <hip/hip_runtime.h>
#include <hip/hip_bf16.h>

#define B_   4
#define LQ_  900
#define D_   256
#define NH_  8
#define DH_  32
#define NL_  4
#define NP_  4
#define DFF_ 1024
#define LIN_ 21760
#define MQ_  (LQ_*B_)    // 3600
#define MV_  (LIN_*B_)   // 87040
#define VALBLKS ((MV_/32)*2)   // 5440 (n-split x2)

typedef __attribute__((ext_vector_type(8))) short bh8;
typedef __attribute__((ext_vector_type(4))) float f32x4;

__device__ __forceinline__ short bf16b(float f) {
    __hip_bfloat16 h = __float2bfloat16(f);
    return *reinterpret_cast<short*>(&h);
}

__device__ __forceinline__ void gload_lds16(const void* g, void* l) {
    __builtin_amdgcn_global_load_lds(
        (const __attribute__((address_space(1))) unsigned int*)g,
        (__attribute__((address_space(3))) unsigned int*)l, 16, 0, 0);
}

__device__ __forceinline__ bh8 af_from_f32(const float* p) {
    float4 v0 = *reinterpret_cast<const float4*>(p);
    float4 v1 = *reinterpret_cast<const float4*>(p + 4);
    return (bh8){ bf16b(v0.x), bf16b(v0.y), bf16b(v0.z), bf16b(v0.w),
                  bf16b(v1.x), bf16b(v1.y), bf16b(v1.z), bf16b(v1.w) };
}

// ---- all weights -> MFMA B-frag images ----
__global__ __launch_bounds__(256)
void wprep_k(const float* __restrict__ Woff, const float* __restrict__ Wattn,
             const float* __restrict__ Wout, const float* __restrict__ W1,
             const float* __restrict__ W2, const float* __restrict__ Wval,
             unsigned char* __restrict__ qkvimg, unsigned char* __restrict__ outimg,
             unsigned char* __restrict__ w1img, unsigned char* __restrict__ w2img,
             unsigned char* __restrict__ valimg)
{
    const int cid = blockIdx.x*256 + threadIdx.x;   // 94208 total
    const float* W; unsigned char* img; int KQ, c;
    if      (cid < 8192)  { W=Woff;  img=qkvimg;           KQ=8;  c=cid;       }
    else if (cid < 12288) { W=Wattn; img=qkvimg + 131072;  KQ=8;  c=cid-8192;  }
    else if (cid < 20480) { W=Wout;  img=outimg;           KQ=8;  c=cid-12288; }
    else if (cid < 53248) { W=W1;    img=w1img;            KQ=8;  c=cid-20480; }
    else if (cid < 86016) { W=W2;    img=w2img;            KQ=32; c=cid-53248; }
    else                  { W=Wval;  img=valimg;           KQ=8;  c=cid-86016; }
    const int K   = KQ*32;
    const int n16 = c & 15, g = (c>>4)&3, t = c>>6;
    const int kq  = t & (KQ-1);
    const int ntile = t >> ((KQ==8) ? 3 : 5);
    const int n = ntile*16 + n16, k0 = kq*32 + g*8;
    float4 v0 = *reinterpret_cast<const float4*>(&W[(size_t)n*K + k0]);
    float4 v1 = *reinterpret_cast<const float4*>(&W[(size_t)n*K + k0 + 4]);
    union { short s[8]; uint4 u; } pk;
    pk.s[0]=bf16b(v0.x); pk.s[1]=bf16b(v0.y); pk.s[2]=bf16b(v0.z); pk.s[3]=bf16b(v0.w);
    pk.s[4]=bf16b(v1.x); pk.s[5]=bf16b(v1.y); pk.s[6]=bf16b(v1.z); pk.s[7]=bf16b(v1.w);
    *reinterpret_cast<uint4*>(img + (size_t)(ntile*KQ + kq)*1024 + (g*16+n16)*16) = pk.u;
}

// ---------------- value GEMM v9 (W register-resident) + qkv tail ----------------
// val: BM=32, BN=128 (bx&1), 256 thr. W: 16 bh8 frags preloaded + asm-pinned (64 VGPR).
// A: 8-phase gload_lds, 3-deep, A-only vmcnt counts (W issued before A -> in-order safe).
__global__ __launch_bounds__(256, 4)
void valqkv_k(const float* __restrict__ A, const unsigned char* __restrict__ Wimg,
              const float* __restrict__ bias, unsigned short* __restrict__ C,
              const unsigned char* __restrict__ mask,
              const float* __restrict__ tgt, const unsigned char* __restrict__ Qimg,
              const float* __restrict__ b_off, const float* __restrict__ b_attn,
              float* __restrict__ Yoff, float* __restrict__ Yattn)
{
    __shared__ __align__(16) unsigned char Al[32768];

    const int tid  = threadIdx.x;
    const int lane = tid & 63;

    if (blockIdx.x < VALBLKS) {
        // ============ value projection ============
        const int wc    = tid >> 6;          // 0..3
        const int mt    = blockIdx.x >> 1;
        const int nhalf = blockIdx.x & 1;
        const int m0    = mt * 32;
        const int r16   = lane & 15;
        const int g     = lane >> 4;

        const unsigned char* Abyte = (const unsigned char*)A;
        const unsigned char* wlane = Wimg + lane*16;

        const int a_row = (tid >> 3) & 31;
        const int a_x   = (tid & 7) * 16;
        const size_t a_src_row = (size_t)(m0 + a_row) * 1024 + (a_x ^ ((a_row & 7) << 4));
        const int a_dst = tid * 16;

#define ISSUE_A(KQ) gload_lds16(Abyte + a_src_row + (KQ)*128, (char*)Al + (KQ)*4096 + a_dst)

        // ---- prologue: ALL W loads first (16), then 3 A chunks ----
        bh8 wreg[2][8];
        #pragma unroll
        for (int i = 0; i < 2; ++i)
            #pragma unroll
            for (int kq = 0; kq < 8; ++kq)
                wreg[i][kq] = *reinterpret_cast<const bh8*>(
                    wlane + (size_t)((nhalf*8 + wc*2 + i)*8 + kq)*1024);

        ISSUE_A(0);
        ISSUE_A(1);
        ISSUE_A(2);

        // W retired (issued before A; A0..A2 still outstanding); pin W in VGPRs
        asm volatile("s_waitcnt vmcnt(3)" ::: "memory");
        #pragma unroll
        for (int i = 0; i < 2; ++i)
            #pragma unroll
            for (int kq = 0; kq < 8; ++kq)
                asm volatile("" : "+v"(wreg[i][kq]));

        f32x4 acc[2][2];
        #pragma unroll
        for (int i = 0; i < 2; ++i)
            #pragma unroll
            for (int j = 0; j < 2; ++j) acc[i][j] = (f32x4){0.f,0.f,0.f,0.f};

        #pragma unroll
        for (int kq = 0; kq < 8; ++kq) {
            if (kq < 6)      asm volatile("s_waitcnt vmcnt(2)" ::: "memory");
            else if (kq == 6) asm volatile("s_waitcnt vmcnt(1)" ::: "memory");
            else              asm volatile("s_waitcnt vmcnt(0)" ::: "memory");
            __builtin_amdgcn_s_barrier();

            bh8 af[2];
            #pragma unroll
            for (int mf = 0; mf < 2; ++mf) {
                const int row = mf*16 + r16;
                const int swz = (row & 7) << 4;
                const char* base = (const char*)Al + kq*4096 + row*128;
                float4 v0 = *reinterpret_cast<const float4*>(base + ((g*32     ) ^ swz));
                float4 v1 = *reinterpret_cast<const float4*>(base + ((g*32 + 16) ^ swz));
                af[mf] = (bh8){ bf16b(v0.x), bf16b(v0.y), bf16b(v0.z), bf16b(v0.w),
                                bf16b(v1.x), bf16b(v1.y), bf16b(v1.z), bf16b(v1.w) };
            }

            if (kq < 5) ISSUE_A(kq + 3);

            #pragma unroll
            for (int mf = 0; mf < 2; ++mf)
                #pragma unroll
                for (int i = 0; i < 2; ++i)
                    acc[mf][i] = __builtin_amdgcn_mfma_f32_16x16x32_bf16(af[mf], wreg[i][kq], acc[mf][i], 0, 0, 0);
        }
#undef ISSUE_A

        float bv[2];
        #pragma unroll
        for (int i = 0; i < 2; ++i) bv[i] = bias[nhalf*128 + wc*32 + i*16 + r16];

        #pragma unroll
        for (int mf = 0; mf < 2; ++mf) {
            #pragma unroll
            for (int r = 0; r < 4; ++r) {
                const int gm = m0 + mf*16 + g*4 + r;
                const bool z = mask[(gm & 3)*LIN_ + (gm >> 2)] != 0;
                #pragma unroll
                for (int i = 0; i < 2; ++i) {
                    float v = acc[mf][i][r] + bv[i];
                    if (z) v = 0.f;
                    C[(size_t)gm*256 + nhalf*128 + wc*32 + i*16 + r16] = (unsigned short)bf16b(v);
                }
            }
        }
    } else {
        // ============ qkv: off+attn projections, 4 waves x 6 n-tiles ============
        const int w   = tid >> 6;
        const int m16 = lane & 15, g = lane >> 4;
        const int m0  = (blockIdx.x - VALBLKS) * 16;

        bh8 af[8];
        #pragma unroll
        for (int kq = 0; kq < 8; ++kq)
            af[kq] = af_from_f32(&tgt[(size_t)(m0 + m16)*256 + kq*32 + g*8]);

        f32x4 acc[6];
        #pragma unroll
        for (int i = 0; i < 6; ++i) acc[i] = (f32x4){0.f,0.f,0.f,0.f};

        #pragma unroll
        for (int i = 0; i < 6; ++i) {
            const int nt = w*6 + i;
            #pragma unroll
            for (int kq = 0; kq < 8; ++kq) {
                bh8 bf = *reinterpret_cast<const bh8*>(Qimg + (size_t)(nt*8 + kq)*1024 + lane*16);
                acc[i] = __builtin_amdgcn_mfma_f32_16x16x32_bf16(af[kq], bf, acc[i], 0, 0, 0);
            }
        }

        #pragma unroll
        for (int i = 0; i < 6; ++i) {
            const int nt = w*6 + i;
            const int j  = nt*16 + m16;
            #pragma unroll
            for (int r = 0; r < 4; ++r) {
                const int m = m0 + g*4 + r;
                if (nt < 16) Yoff[(size_t)m*256 + j] = acc[i][r] + b_off[j];
                else         Yattn[(size_t)m*128 + (j-256)] = acc[i][r] + b_attn[j-256];
            }
        }
    }
}

// ---------------- fused out-proj + LN1 + FFN + LN3 (R18) ----------------
__global__ __launch_bounds__(1024, 2)
void outffn_k(const float* __restrict__ Amsda, const unsigned char* __restrict__ Oimg,
              const float* __restrict__ b_out, const float* __restrict__ res,
              const float* __restrict__ l1g, const float* __restrict__ l1b,
              const unsigned char* __restrict__ W1img, const float* __restrict__ b1,
              const unsigned char* __restrict__ W2img, const float* __restrict__ b2,
              const float* __restrict__ l3g, const float* __restrict__ l3b,
              float* __restrict__ Yout)
{
    __shared__ float sln[16][256];
    __shared__ __align__(16) short hl[2][16*272];

    const int tid = threadIdx.x, lane = tid & 63, w = tid >> 6;
    const int m16 = lane & 15, g = lane >> 4;
    const int m0 = blockIdx.x * 16;

    {
        bh8 af[8];
        #pragma unroll
        for (int kq = 0; kq < 8; ++kq)
            af[kq] = af_from_f32(&Amsda[(size_t)(m0 + m16)*256 + kq*32 + g*8]);

        f32x4 acc = (f32x4){0.f,0.f,0.f,0.f};
        #pragma unroll
        for (int kq = 0; kq < 8; ++kq) {
            bh8 bf = *reinterpret_cast<const bh8*>(Oimg + (size_t)(w*8 + kq)*1024 + lane*16);
            acc = __builtin_amdgcn_mfma_f32_16x16x32_bf16(af[kq], bf, acc, 0, 0, 0);
        }

        const int j = w*16 + m16;
        #pragma unroll
        for (int r = 0; r < 4; ++r) {
            const int ml = g*4 + r;
            sln[ml][j] = acc[r] + b_out[j] + res[(size_t)(m0 + ml)*256 + j];
        }
    }
    __syncthreads();

    {
        const int row = w, l2 = lane;
        float v[4], s1 = 0.f, s2 = 0.f;
        #pragma unroll
        for (int c = 0; c < 4; ++c) {
            v[c] = sln[row][l2 + c*64];
            s1 += v[c]; s2 += v[c]*v[c];
        }
        #pragma unroll
        for (int o = 32; o >= 1; o >>= 1) {
            s1 += __shfl_xor(s1, o, 64);
            s2 += __shfl_xor(s2, o, 64);
        }
        const float mu  = s1 * (1.f/256.f);
        const float var = s2 * (1.f/256.f) - mu*mu;
        const float is  = rsqrtf(var + 1e-5f);
        #pragma unroll
        for (int c = 0; c < 4; ++c) {
            const int jj = l2 + c*64;
            sln[row][jj] = (v[c] - mu) * is * l1g[jj] + l1b[jj];
        }
    }
    __syncthreads();

    bh8 af1[8];
    #pragma unroll
    for (int kq = 0; kq < 8; ++kq)
        af1[kq] = af_from_f32(&sln[m16][kq*32 + g*8]);

    f32x4 yacc = (f32x4){0.f,0.f,0.f,0.f};

    int buf = 0;
    #pragma unroll
    for (int fc = 0; fc < 4; ++fc) {
        const int ftile_g = fc*16 + w;
        f32x4 hacc = (f32x4){0.f,0.f,0.f,0.f};
        #pragma unroll
        for (int kq = 0; kq < 8; ++kq) {
            bh8 bf = *reinterpret_cast<const bh8*>(W1img + (size_t)(ftile_g*8 + kq)*1024 + lane*16);
            hacc = __builtin_amdgcn_mfma_f32_16x16x32_bf16(af1[kq], bf, hacc, 0, 0, 0);
        }
        const float bb = b1[ftile_g*16 + m16];
        #pragma unroll
        for (int r = 0; r < 4; ++r) {
            const float v = fmaxf(hacc[r] + bb, 0.f);
            hl[buf][(g*4 + r)*272 + w*16 + m16] = bf16b(v);
        }
        __syncthreads();
        bh8 a2[8];
        #pragma unroll
        for (int kqf = 0; kqf < 8; ++kqf)
            a2[kqf] = *reinterpret_cast<const bh8*>((const char*)&hl[buf][0]
                + m16*544 + (kqf*32 + g*8)*2);
        #pragma unroll
        for (int kqf = 0; kqf < 8; ++kqf) {
            const int kq2 = fc*8 + kqf;
            bh8 bf = *reinterpret_cast<const bh8*>(W2img + (size_t)(w*32 + kq2)*1024 + lane*16);
            yacc = __builtin_amdgcn_mfma_f32_16x16x32_bf16(a2[kqf], bf, yacc, 0, 0, 0);
        }
        buf ^= 1;
    }

    {
        const int j = w*16 + m16;
        #pragma unroll
        for (int r = 0; r < 4; ++r) {
            const int ml = g*4 + r;
            sln[ml][j] = yacc[r] + b2[j] + sln[ml][j];
        }
    }
    __syncthreads();

    {
        const int row = w, l2 = lane;
        float v[4], s1 = 0.f, s2 = 0.f;
        #pragma unroll
        for (int c = 0; c < 4; ++c) {
            v[c] = sln[row][l2 + c*64];
            s1 += v[c]; s2 += v[c]*v[c];
        }
        #pragma unroll
        for (int o = 32; o >= 1; o >>= 1) {
            s1 += __shfl_xor(s1, o, 64);
            s2 += __shfl_xor(s2, o, 64);
        }
        const float mu  = s1 * (1.f/256.f);
        const float var = s2 * (1.f/256.f) - mu*mu;
        const float is  = rsqrtf(var + 1e-5f);
        #pragma unroll
        for (int c = 0; c < 4; ++c) {
            const int jj = l2 + c*64;
            Yout[(size_t)(m0 + row)*256 + jj] = (v[c] - mu) * is * l3g[jj] + l3b[jj];
        }
    }
}

// ---------------- deformable sampling v2: ushort2 gathers, 2 rows/block ----------------
__global__ __launch_bounds__(256)
void msda_k(const float* __restrict__ off,
            const float* __restrict__ attnlog,
            const float* __restrict__ refp,
            const __hip_bfloat16* __restrict__ value,
            float* __restrict__ out)
{
    const int hp = threadIdx.x >> 7;          // 0/1: row within block
    const int dd = threadIdx.x & 127;         // 0..127
    const int d0 = dd * 2;
    const int m  = blockIdx.x*2 + hp;
    const int b  = m & 3;
    const int h  = dd >> 4;                   // d0>>5

    __shared__ float s_off[2][256];
    __shared__ float s_al[2][128];
    __shared__ float s_ref[2][NL_*2];
    {
        const int t2 = threadIdx.x & 127;
        s_off[hp][t2]       = off[(size_t)m*256 + t2];
        s_off[hp][t2 + 128] = off[(size_t)m*256 + t2 + 128];
        if (t2 < 128) s_al[hp][t2] = attnlog[(size_t)m*128 + t2];
        if (t2 < NL_*2) s_ref[hp][t2] = refp[(size_t)m*(NL_*2) + t2];
    }
    __syncthreads();

    float mx = -1e30f;
    #pragma unroll
    for (int t = 0; t < 16; ++t) mx = fmaxf(mx, s_al[hp][h*16 + t]);
    float e[16], ssum = 0.f;
    #pragma unroll
    for (int t = 0; t < 16; ++t) { e[t] = __expf(s_al[hp][h*16 + t] - mx); ssum += e[t]; }
    const float inv = 1.f / ssum;

    const int HS[4] = {128, 64, 32, 16};
    const int ST[4] = {0, 16384, 20480, 21504};

    float acc0 = 0.f, acc1 = 0.f;
    #pragma unroll
    for (int l = 0; l < NL_; ++l) {
        const int H = HS[l], W = HS[l], st = ST[l];
        const float rx = s_ref[hp][l*2+0], ry = s_ref[hp][l*2+1];
        #pragma unroll
        for (int p = 0; p < NP_; ++p) {
            const int base = ((h*NL_ + l)*NP_ + p);
            const float a  = e[l*4 + p] * inv;
            const float ox = s_off[hp][base*2+0], oy = s_off[hp][base*2+1];
            const float x = rx*(float)W + ox - 0.5f;
            const float y = ry*(float)H + oy - 0.5f;
            const float x0f = floorf(x), y0f = floorf(y);
            const int x0 = (int)x0f, y0 = (int)y0f;
            const float wx1 = x - x0f, wy1 = y - y0f;
            const float wx0 = 1.f - wx1, wy0 = 1.f - wy1;
            #pragma unroll
            for (int t = 0; t < 4; ++t) {
                const int xi = x0 + (t & 1);
                const int yi = y0 + (t >> 1);
                const float wgt = (t==0 ? wx0*wy0 : t==1 ? wx1*wy0 : t==2 ? wx0*wy1 : wx1*wy1);
                if (xi >= 0 && xi < W && yi >= 0 && yi < H) {
                    const size_t idx = (size_t)(st + yi*W + xi);
                    const unsigned int v = *reinterpret_cast<const unsigned int*>(
                        &value[(idx*B_ + b)*D_ + d0]);
                    const float f0 = __uint_as_float(v << 16);
                    const float f1 = __uint_as_float(v & 0xffff0000u);
                    const float aw = a * wgt;
                    acc0 = fmaf(aw, f0, acc0);
                    acc1 = fmaf(aw, f1, acc1);
                }
            }
        }
    }
    float2 o2 = { acc0, acc1 };
    *reinterpret_cast<float2*>(&out[(size_t)m*256 + d0]) = o2;
}

extern "C" void kernel_launch(void* const* d_in, const int* in_sizes, int n_in,
                              void* d_out, int out_size, void* d_ws, size_t ws_size,
                              hipStream_t stream)
{
    const float* tgt    = (const float*)d_in[0];
    const float* refp   = (const float*)d_in[1];
    const float* mem    = (const float*)d_in[2];
    const float* W_off  = (const float*)d_in[3];
    const float* b_off  = (const float*)d_in[4];
    const float* W_attn = (const float*)d_in[5];
    const float* b_attn = (const float*)d_in[6];
    const float* W_val  = (const float*)d_in[7];
    const float* b_val  = (const float*)d_in[8];
    const float* W_out  = (const float*)d_in[9];
    const float* b_out  = (const float*)d_in[10];
    const float* ln1g   = (const float*)d_in[11];
    const float* ln1b   = (const float*)d_in[12];
    const float* W1     = (const float*)d_in[13];
    const float* b1     = (const float*)d_in[14];
    const float* W2     = (const float*)d_in[15];
    const float* b2     = (const float*)d_in[16];
    const float* ln3g   = (const float*)d_in[17];
    const float* ln3b   = (const float*)d_in[18];
    const unsigned char* mask = (const unsigned char*)d_in[21];
    float* out = (float*)d_out;

    char* p = (char*)d_ws;
    __hip_bfloat16* value = (__hip_bfloat16*)p; p += (size_t)MV_*D_*2;   // 44.6 MB
    float* offb = (float*)p; p += (size_t)MQ_*256*4;
    float* attl = (float*)p; p += (size_t)MQ_*128*4;
    float* msda = (float*)p; p += (size_t)MQ_*256*4;
    unsigned char* qkvimg = (unsigned char*)p; p += 196608;
    unsigned char* outimg = (unsigned char*)p; p += 131072;
    unsigned char* w1img  = (unsigned char*)p; p += 524288;
    unsigned char* w2img  = (unsigned char*)p; p += 524288;
    unsigned char* valimg = (unsigned char*)p; p += 131072;
    (void)ws_size; (void)in_sizes; (void)n_in; (void)out_size;

    // 0) weight B-frag images
    wprep_k<<<dim3(368), dim3(256), 0, stream>>>(W_off, W_attn, W_out, W1, W2, W_val,
                                                 qkvimg, outimg, w1img, w2img, valimg);
    // 1) value projection (W reg-resident) + qkv projections
    valqkv_k<<<dim3(VALBLKS + MQ_/16), dim3(256), 0, stream>>>(
        mem, valimg, b_val, (unsigned short*)value, mask,
        tgt, qkvimg, b_off, b_attn, offb, attl);
    // 2) deformable sampling (ushort2, 2 rows/block)
    msda_k<<<dim3(MQ_/2), dim3(256), 0, stream>>>(offb, attl, refp, value, msda);
    // 3) out-proj + LN1 + FFN + LN3 -> out
    outffn_k<<<dim3(MQ_/16), dim3(1024), 0, stream>>>(
        msda, outimg, b_out, tgt, ln1g, ln1b,
        w1img, b1, w2img, b2, ln3g, ln3b, out);
}

// Round 20
// 99.308 us; speedup vs baseline: 1.2710x; 1.1285x over previous
//
#include <hip/hip_runtime.h>
#include <hip/hip_bf16.h>

#define B_   4
#define LQ_  900
#define D_   256
#define NH_  8
#define DH_  32
#define NL_  4
#define NP_  4
#define DFF_ 1024
#define LIN_ 21760
#define MQ_  (LQ_*B_)    // 3600
#define MV_  (LIN_*B_)   // 87040
#define VALBLKS (MV_/32) // 2720

typedef __attribute__((ext_vector_type(8))) short bh8;
typedef __attribute__((ext_vector_type(4))) float f32x4;

__device__ __forceinline__ short bf16b(float f) {
    __hip_bfloat16 h = __float2bfloat16(f);
    return *reinterpret_cast<short*>(&h);
}

__device__ __forceinline__ void gload_lds16(const void* g, void* l) {
    __builtin_amdgcn_global_load_lds(
        (const __attribute__((address_space(1))) unsigned int*)g,
        (__attribute__((address_space(3))) unsigned int*)l, 16, 0, 0);
}

__device__ __forceinline__ bh8 af_from_f32(const float* p) {
    float4 v0 = *reinterpret_cast<const float4*>(p);
    float4 v1 = *reinterpret_cast<const float4*>(p + 4);
    return (bh8){ bf16b(v0.x), bf16b(v0.y), bf16b(v0.z), bf16b(v0.w),
                  bf16b(v1.x), bf16b(v1.y), bf16b(v1.z), bf16b(v1.w) };
}

// ---- all weights -> MFMA B-frag images ----
__global__ __launch_bounds__(256)
void wprep_k(const float* __restrict__ Woff, const float* __restrict__ Wattn,
             const float* __restrict__ Wout, const float* __restrict__ W1,
             const float* __restrict__ W2, const float* __restrict__ Wval,
             unsigned char* __restrict__ qkvimg, unsigned char* __restrict__ outimg,
             unsigned char* __restrict__ w1img, unsigned char* __restrict__ w2img,
             unsigned char* __restrict__ valimg)
{
    const int cid = blockIdx.x*256 + threadIdx.x;   // 94208 total
    const float* W; unsigned char* img; int KQ, c;
    if      (cid < 8192)  { W=Woff;  img=qkvimg;           KQ=8;  c=cid;       }
    else if (cid < 12288) { W=Wattn; img=qkvimg + 131072;  KQ=8;  c=cid-8192;  }
    else if (cid < 20480) { W=Wout;  img=outimg;           KQ=8;  c=cid-12288; }
    else if (cid < 53248) { W=W1;    img=w1img;            KQ=8;  c=cid-20480; }
    else if (cid < 86016) { W=W2;    img=w2img;            KQ=32; c=cid-53248; }
    else                  { W=Wval;  img=valimg;           KQ=8;  c=cid-86016; }
    const int K   = KQ*32;
    const int n16 = c & 15, g = (c>>4)&3, t = c>>6;
    const int kq  = t & (KQ-1);
    const int ntile = t >> ((KQ==8) ? 3 : 5);
    const int n = ntile*16 + n16, k0 = kq*32 + g*8;
    float4 v0 = *reinterpret_cast<const float4*>(&W[(size_t)n*K + k0]);
    float4 v1 = *reinterpret_cast<const float4*>(&W[(size_t)n*K + k0 + 4]);
    union { short s[8]; uint4 u; } pk;
    pk.s[0]=bf16b(v0.x); pk.s[1]=bf16b(v0.y); pk.s[2]=bf16b(v0.z); pk.s[3]=bf16b(v0.w);
    pk.s[4]=bf16b(v1.x); pk.s[5]=bf16b(v1.y); pk.s[6]=bf16b(v1.z); pk.s[7]=bf16b(v1.w);
    *reinterpret_cast<uint4*>(img + (size_t)(ntile*KQ + kq)*1024 + (g*16+n16)*16) = pk.u;
}

// ---------------- value GEMM (R14/R18 best body) + qkv tail blocks ----------------
__global__ __launch_bounds__(256, 4)
void valqkv_k(const float* __restrict__ A, const unsigned char* __restrict__ Wimg,
              const float* __restrict__ bias, unsigned short* __restrict__ C,
              const unsigned char* __restrict__ mask,
              const float* __restrict__ tgt, const unsigned char* __restrict__ Qimg,
              const float* __restrict__ b_off, const float* __restrict__ b_attn,
              float* __restrict__ Yoff, float* __restrict__ Yattn)
{
    __shared__ __align__(16) unsigned char Al[32768];

    const int tid  = threadIdx.x;
    const int lane = tid & 63;

    if (blockIdx.x < VALBLKS) {
        // ============ value projection: R14 8-phase counted-vmcnt body ============
        const int wc   = tid >> 6;
        const int m0   = blockIdx.x * 32;
        const int r16  = lane & 15;
        const int g    = lane >> 4;

        const unsigned char* Abyte = (const unsigned char*)A;
        const unsigned char* wlane = Wimg + lane*16;

        const int a_row = (tid >> 3) & 31;
        const int a_x   = (tid & 7) * 16;
        const size_t a_src_row = (size_t)(m0 + a_row) * 1024 + (a_x ^ ((a_row & 7) << 4));
        const int a_dst = tid * 16;

#define ISSUE_A(KQ) gload_lds16(Abyte + a_src_row + (KQ)*128, (char*)Al + (KQ)*4096 + a_dst)
#define ISSUE_W(KQ, SLOT)                                                              \
    do { _Pragma("unroll")                                                             \
        for (int i_ = 0; i_ < 4; ++i_)                                                 \
            bfr[SLOT][i_] = *reinterpret_cast<const bh8*>(                             \
                wlane + (size_t)((wc*4 + i_)*8 + (KQ))*1024);                          \
    } while (0)

        bh8 bfr[3][4];

        ISSUE_A(0);
        ISSUE_W(0, 0);
        ISSUE_W(1, 1);
        ISSUE_A(1);
        ISSUE_A(2);

        f32x4 acc[2][4];
        #pragma unroll
        for (int i = 0; i < 2; ++i)
            #pragma unroll
            for (int j = 0; j < 4; ++j) acc[i][j] = (f32x4){0.f,0.f,0.f,0.f};

        #pragma unroll
        for (int kq = 0; kq < 8; ++kq) {
            if (kq < 6)      asm volatile("s_waitcnt vmcnt(6)" ::: "memory");
            else if (kq == 6) asm volatile("s_waitcnt vmcnt(5)" ::: "memory");
            else              asm volatile("s_waitcnt vmcnt(0)" ::: "memory");
            __builtin_amdgcn_s_barrier();

            bh8 af[2];
            #pragma unroll
            for (int mf = 0; mf < 2; ++mf) {
                const int row = mf*16 + r16;
                const int swz = (row & 7) << 4;
                const char* base = (const char*)Al + kq*4096 + row*128;
                float4 v0 = *reinterpret_cast<const float4*>(base + ((g*32     ) ^ swz));
                float4 v1 = *reinterpret_cast<const float4*>(base + ((g*32 + 16) ^ swz));
                af[mf] = (bh8){ bf16b(v0.x), bf16b(v0.y), bf16b(v0.z), bf16b(v0.w),
                                bf16b(v1.x), bf16b(v1.y), bf16b(v1.z), bf16b(v1.w) };
            }

            if (kq == 0) { ISSUE_W(2, 2); ISSUE_A(3); }
            if (kq == 1) { ISSUE_W(3, 0); ISSUE_A(4); }
            if (kq == 2) { ISSUE_W(4, 1); ISSUE_A(5); }
            if (kq == 3) { ISSUE_W(5, 2); ISSUE_A(6); }
            if (kq == 4) { ISSUE_W(6, 0); ISSUE_A(7); }
            if (kq == 5) { ISSUE_W(7, 1); }

            #pragma unroll
            for (int mf = 0; mf < 2; ++mf)
                #pragma unroll
                for (int i = 0; i < 4; ++i)
                    acc[mf][i] = __builtin_amdgcn_mfma_f32_16x16x32_bf16(af[mf], bfr[kq % 3][i], acc[mf][i], 0, 0, 0);
        }
#undef ISSUE_A
#undef ISSUE_W

        float bv[4];
        #pragma unroll
        for (int i = 0; i < 4; ++i) bv[i] = bias[wc*64 + i*16 + r16];

        #pragma unroll
        for (int mf = 0; mf < 2; ++mf) {
            #pragma unroll
            for (int r = 0; r < 4; ++r) {
                const int gm = m0 + mf*16 + g*4 + r;
                const bool z = mask[(gm & 3)*LIN_ + (gm >> 2)] != 0;
                #pragma unroll
                for (int i = 0; i < 4; ++i) {
                    float v = acc[mf][i][r] + bv[i];
                    if (z) v = 0.f;
                    C[(size_t)gm*256 + wc*64 + i*16 + r16] = (unsigned short)bf16b(v);
                }
            }
        }
    } else {
        // ============ qkv: off+attn projections, 4 waves x 6 n-tiles ============
        const int w   = tid >> 6;
        const int m16 = lane & 15, g = lane >> 4;
        const int m0  = (blockIdx.x - VALBLKS) * 16;

        bh8 af[8];
        #pragma unroll
        for (int kq = 0; kq < 8; ++kq)
            af[kq] = af_from_f32(&tgt[(size_t)(m0 + m16)*256 + kq*32 + g*8]);

        f32x4 acc[6];
        #pragma unroll
        for (int i = 0; i < 6; ++i) acc[i] = (f32x4){0.f,0.f,0.f,0.f};

        #pragma unroll
        for (int i = 0; i < 6; ++i) {
            const int nt = w*6 + i;
            #pragma unroll
            for (int kq = 0; kq < 8; ++kq) {
                bh8 bf = *reinterpret_cast<const bh8*>(Qimg + (size_t)(nt*8 + kq)*1024 + lane*16);
                acc[i] = __builtin_amdgcn_mfma_f32_16x16x32_bf16(af[kq], bf, acc[i], 0, 0, 0);
            }
        }

        #pragma unroll
        for (int i = 0; i < 6; ++i) {
            const int nt = w*6 + i;
            const int j  = nt*16 + m16;
            #pragma unroll
            for (int r = 0; r < 4; ++r) {
                const int m = m0 + g*4 + r;
                if (nt < 16) Yoff[(size_t)m*256 + j] = acc[i][r] + b_off[j];
                else         Yattn[(size_t)m*128 + (j-256)] = acc[i][r] + b_attn[j-256];
            }
        }
    }
}

// ---------------- fused out-proj + LN1 + FFN + LN3 (R18) ----------------
__global__ __launch_bounds__(1024, 2)
void outffn_k(const float* __restrict__ Amsda, const unsigned char* __restrict__ Oimg,
              const float* __restrict__ b_out, const float* __restrict__ res,
              const float* __restrict__ l1g, const float* __restrict__ l1b,
              const unsigned char* __restrict__ W1img, const float* __restrict__ b1,
              const unsigned char* __restrict__ W2img, const float* __restrict__ b2,
              const float* __restrict__ l3g, const float* __restrict__ l3b,
              float* __restrict__ Yout)
{
    __shared__ float sln[16][256];
    __shared__ __align__(16) short hl[2][16*272];

    const int tid = threadIdx.x, lane = tid & 63, w = tid >> 6;
    const int m16 = lane & 15, g = lane >> 4;
    const int m0 = blockIdx.x * 16;

    {
        bh8 af[8];
        #pragma unroll
        for (int kq = 0; kq < 8; ++kq)
            af[kq] = af_from_f32(&Amsda[(size_t)(m0 + m16)*256 + kq*32 + g*8]);

        f32x4 acc = (f32x4){0.f,0.f,0.f,0.f};
        #pragma unroll
        for (int kq = 0; kq < 8; ++kq) {
            bh8 bf = *reinterpret_cast<const bh8*>(Oimg + (size_t)(w*8 + kq)*1024 + lane*16);
            acc = __builtin_amdgcn_mfma_f32_16x16x32_bf16(af[kq], bf, acc, 0, 0, 0);
        }

        const int j = w*16 + m16;
        #pragma unroll
        for (int r = 0; r < 4; ++r) {
            const int ml = g*4 + r;
            sln[ml][j] = acc[r] + b_out[j] + res[(size_t)(m0 + ml)*256 + j];
        }
    }
    __syncthreads();

    {
        const int row = w, l2 = lane;
        float v[4], s1 = 0.f, s2 = 0.f;
        #pragma unroll
        for (int c = 0; c < 4; ++c) {
            v[c] = sln[row][l2 + c*64];
            s1 += v[c]; s2 += v[c]*v[c];
        }
        #pragma unroll
        for (int o = 32; o >= 1; o >>= 1) {
            s1 += __shfl_xor(s1, o, 64);
            s2 += __shfl_xor(s2, o, 64);
        }
        const float mu  = s1 * (1.f/256.f);
        const float var = s2 * (1.f/256.f) - mu*mu;
        const float is  = rsqrtf(var + 1e-5f);
        #pragma unroll
        for (int c = 0; c < 4; ++c) {
            const int jj = l2 + c*64;
            sln[row][jj] = (v[c] - mu) * is * l1g[jj] + l1b[jj];
        }
    }
    __syncthreads();

    bh8 af1[8];
    #pragma unroll
    for (int kq = 0; kq < 8; ++kq)
        af1[kq] = af_from_f32(&sln[m16][kq*32 + g*8]);

    f32x4 yacc = (f32x4){0.f,0.f,0.f,0.f};

    int buf = 0;
    #pragma unroll
    for (int fc = 0; fc < 4; ++fc) {
        const int ftile_g = fc*16 + w;
        f32x4 hacc = (f32x4){0.f,0.f,0.f,0.f};
        #pragma unroll
        for (int kq = 0; kq < 8; ++kq) {
            bh8 bf = *reinterpret_cast<const bh8*>(W1img + (size_t)(ftile_g*8 + kq)*1024 + lane*16);
            hacc = __builtin_amdgcn_mfma_f32_16x16x32_bf16(af1[kq], bf, hacc, 0, 0, 0);
        }
        const float bb = b1[ftile_g*16 + m16];
        #pragma unroll
        for (int r = 0; r < 4; ++r) {
            const float v = fmaxf(hacc[r] + bb, 0.f);
            hl[buf][(g*4 + r)*272 + w*16 + m16] = bf16b(v);
        }
        __syncthreads();
        bh8 a2[8];
        #pragma unroll
        for (int kqf = 0; kqf < 8; ++kqf)
            a2[kqf] = *reinterpret_cast<const bh8*>((const char*)&hl[buf][0]
                + m16*544 + (kqf*32 + g*8)*2);
        #pragma unroll
        for (int kqf = 0; kqf < 8; ++kqf) {
            const int kq2 = fc*8 + kqf;
            bh8 bf = *reinterpret_cast<const bh8*>(W2img + (size_t)(w*32 + kq2)*1024 + lane*16);
            yacc = __builtin_amdgcn_mfma_f32_16x16x32_bf16(a2[kqf], bf, yacc, 0, 0, 0);
        }
        buf ^= 1;
    }

    {
        const int j = w*16 + m16;
        #pragma unroll
        for (int r = 0; r < 4; ++r) {
            const int ml = g*4 + r;
            sln[ml][j] = yacc[r] + b2[j] + sln[ml][j];
        }
    }
    __syncthreads();

    {
        const int row = w, l2 = lane;
        float v[4], s1 = 0.f, s2 = 0.f;
        #pragma unroll
        for (int c = 0; c < 4; ++c) {
            v[c] = sln[row][l2 + c*64];
            s1 += v[c]; s2 += v[c]*v[c];
        }
        #pragma unroll
        for (int o = 32; o >= 1; o >>= 1) {
            s1 += __shfl_xor(s1, o, 64);
            s2 += __shfl_xor(s2, o, 64);
        }
        const float mu  = s1 * (1.f/256.f);
        const float var = s2 * (1.f/256.f) - mu*mu;
        const float is  = rsqrtf(var + 1e-5f);
        #pragma unroll
        for (int c = 0; c < 4; ++c) {
            const int jj = l2 + c*64;
            Yout[(size_t)(m0 + row)*256 + jj] = (v[c] - mu) * is * l3g[jj] + l3b[jj];
        }
    }
}

// ---------------- deformable sampling v2: ushort2 gathers, 2 rows/block (R19) ----------------
__global__ __launch_bounds__(256)
void msda_k(const float* __restrict__ off,
            const float* __restrict__ attnlog,
            const float* __restrict__ refp,
            const __hip_bfloat16* __restrict__ value,
            float* __restrict__ out)
{
    const int hp = threadIdx.x >> 7;
    const int dd = threadIdx.x & 127;
    const int d0 = dd * 2;
    const int m  = blockIdx.x*2 + hp;
    const int b  = m & 3;
    const int h  = dd >> 4;

    __shared__ float s_off[2][256];
    __shared__ float s_al[2][128];
    __shared__ float s_ref[2][NL_*2];
    {
        const int t2 = threadIdx.x & 127;
        s_off[hp][t2]       = off[(size_t)m*256 + t2];
        s_off[hp][t2 + 128] = off[(size_t)m*256 + t2 + 128];
        if (t2 < 128) s_al[hp][t2] = attnlog[(size_t)m*128 + t2];
        if (t2 < NL_*2) s_ref[hp][t2] = refp[(size_t)m*(NL_*2) + t2];
    }
    __syncthreads();

    float mx = -1e30f;
    #pragma unroll
    for (int t = 0; t < 16; ++t) mx = fmaxf(mx, s_al[hp][h*16 + t]);
    float e[16], ssum = 0.f;
    #pragma unroll
    for (int t = 0; t < 16; ++t) { e[t] = __expf(s_al[hp][h*16 + t] - mx); ssum += e[t]; }
    const float inv = 1.f / ssum;

    const int HS[4] = {128, 64, 32, 16};
    const int ST[4] = {0, 16384, 20480, 21504};

    float acc0 = 0.f, acc1 = 0.f;
    #pragma unroll
    for (int l = 0; l < NL_; ++l) {
        const int H = HS[l], W = HS[l], st = ST[l];
        const float rx = s_ref[hp][l*2+0], ry = s_ref[hp][l*2+1];
        #pragma unroll
        for (int p = 0; p < NP_; ++p) {
            const int base = ((h*NL_ + l)*NP_ + p);
            const float a  = e[l*4 + p] * inv;
            const float ox = s_off[hp][base*2+0], oy = s_off[hp][base*2+1];
            const float x = rx*(float)W + ox - 0.5f;
            const float y = ry*(float)H + oy - 0.5f;
            const float x0f = floorf(x), y0f = floorf(y);
            const int x0 = (int)x0f, y0 = (int)y0f;
            const float wx1 = x - x0f, wy1 = y - y0f;
            const float wx0 = 1.f - wx1, wy0 = 1.f - wy1;
            #pragma unroll
            for (int t = 0; t < 4; ++t) {
                const int xi = x0 + (t & 1);
                const int yi = y0 + (t >> 1);
                const float wgt = (t==0 ? wx0*wy0 : t==1 ? wx1*wy0 : t==2 ? wx0*wy1 : wx1*wy1);
                if (xi >= 0 && xi < W && yi >= 0 && yi < H) {
                    const size_t idx = (size_t)(st + yi*W + xi);
                    const unsigned int v = *reinterpret_cast<const unsigned int*>(
                        &value[(idx*B_ + b)*D_ + d0]);
                    const float f0 = __uint_as_float(v << 16);
                    const float f1 = __uint_as_float(v & 0xffff0000u);
                    const float aw = a * wgt;
                    acc0 = fmaf(aw, f0, acc0);
                    acc1 = fmaf(aw, f1, acc1);
                }
            }
        }
    }
    float2 o2 = { acc0, acc1 };
    *reinterpret_cast<float2*>(&out[(size_t)m*256 + d0]) = o2;
}

extern "C" void kernel_launch(void* const* d_in, const int* in_sizes, int n_in,
                              void* d_out, int out_size, void* d_ws, size_t ws_size,
                              hipStream_t stream)
{
    const float* tgt    = (const float*)d_in[0];
    const float* refp   = (const float*)d_in[1];
    const float* mem    = (const float*)d_in[2];
    const float* W_off  = (const float*)d_in[3];
    const float* b_off  = (const float*)d_in[4];
    const float* W_attn = (const float*)d_in[5];
    const float* b_attn = (const float*)d_in[6];
    const float* W_val  = (const float*)d_in[7];
    const float* b_val  = (const float*)d_in[8];
    const float* W_out  = (const float*)d_in[9];
    const float* b_out  = (const float*)d_in[10];
    const float* ln1g   = (const float*)d_in[11];
    const float* ln1b   = (const float*)d_in[12];
    const float* W1     = (const float*)d_in[13];
    const float* b1     = (const float*)d_in[14];
    const float* W2     = (const float*)d_in[15];
    const float* b2     = (const float*)d_in[16];
    const float* ln3g   = (const float*)d_in[17];
    const float* ln3b   = (const float*)d_in[18];
    const unsigned char* mask = (const unsigned char*)d_in[21];
    float* out = (float*)d_out;

    char* p = (char*)d_ws;
    __hip_bfloat16* value = (__hip_bfloat16*)p; p += (size_t)MV_*D_*2;   // 44.6 MB
    float* offb = (float*)p; p += (size_t)MQ_*256*4;
    float* attl = (float*)p; p += (size_t)MQ_*128*4;
    float* msda = (float*)p; p += (size_t)MQ_*256*4;
    unsigned char* qkvimg = (unsigned char*)p; p += 196608;
    unsigned char* outimg = (unsigned char*)p; p += 131072;
    unsigned char* w1img  = (unsigned char*)p; p += 524288;
    unsigned char* w2img  = (unsigned char*)p; p += 524288;
    unsigned char* valimg = (unsigned char*)p; p += 131072;
    (void)ws_size; (void)in_sizes; (void)n_in; (void)out_size;

    // 0) weight B-frag images
    wprep_k<<<dim3(368), dim3(256), 0, stream>>>(W_off, W_attn, W_out, W1, W2, W_val,
                                                 qkvimg, outimg, w1img, w2img, valimg);
    // 1) value projection + qkv projections (one dispatch)
    valqkv_k<<<dim3(VALBLKS + MQ_/16), dim3(256), 0, stream>>>(
        mem, valimg, b_val, (unsigned short*)value, mask,
        tgt, qkvimg, b_off, b_attn, offb, attl);
    // 2) deformable sampling (ushort2, 2 rows/block)
    msda_k<<<dim3(MQ_/2), dim3(256), 0, stream>>>(offb, attl, refp, value, msda);
    // 3) out-proj + LN1 + FFN + LN3 -> out
    outffn_k<<<dim3(MQ_/16), dim3(1024), 0, stream>>>(
        msda, outimg, b_out, tgt, ln1g, ln1b,
        w1img, b1, w2img, b2, ln3g, ln3b, out);
}